// Round 16
// baseline (506.199 us; speedup 1.0000x reference)
//
#include <hip/hip_runtime.h>
#include <hip/hip_bf16.h>

#define NC 4096
#define GG 1024
#define DM 128
#define HH 4
#define HDIM 32
#define FF 512
#define LL 2
#define NHCI 2
#define NSF 16
#define LDV (NC+64)
#define LS2 (100.0f*100.0f)
#define QSCALE 0.17677669529663687f

typedef __bf16 bf16x8 __attribute__((ext_vector_type(8)));
typedef __bf16 bf16x4 __attribute__((ext_vector_type(4)));
typedef float  f32x4  __attribute__((ext_vector_type(4)));

// bijective XCD-chunk swizzle (m204)
__device__ __forceinline__ int xcd_swz(int orig, int nwg)
{
    int q = nwg >> 3, r = nwg & 7;
    int xcd = orig & 7, idx = orig >> 3;
    return (xcd < r ? xcd*(q+1) : r*(q+1) + (xcd-r)*q) + idx;
}

// ================= bf16 MFMA GEMM (m97 structure, fused epilogues) ==========
enum { MM_NONE=0, MM_BIAS, MM_BIAS_B16, MM_RELU_B16, MM_B16, MM_SIGSP_B16, MM_DIST };

template<int EM>
__launch_bounds__(256)
__global__ void mgemm_k(const __bf16* __restrict__ A, int lda,
                        const __bf16* __restrict__ BT, int ldb,
                        const float* __restrict__ aux1,
                        float* __restrict__ C, __bf16* __restrict__ Cb, int ldc,
                        int M, int N, int K, float alpha,
                        const float* __restrict__ aux2,
                        const int* __restrict__ flag)
{
    if (flag && *flag == 0) return;
    __shared__ __align__(16) __bf16 As[128][32];
    __shared__ __align__(16) __bf16 Bs[128][32];
    const int tid  = threadIdx.x;
    const int lane = tid & 63;
    const int wid  = tid >> 6;
    const int wm = wid >> 1, wn = wid & 1;
    const int nwg  = gridDim.x * gridDim.y;
    const int wg   = xcd_swz(blockIdx.y * gridDim.x + blockIdx.x, nwg);
    const int bm = (wg / gridDim.x) * 128, bn = (wg % gridDim.x) * 128;

    f32x4 acc[4][4];
    #pragma unroll
    for (int m=0;m<4;m++)
        #pragma unroll
        for (int n=0;n<4;n++) acc[m][n] = (f32x4){0.f,0.f,0.f,0.f};

    const int c0 = wid*64 + lane, c1 = c0 + 256;
    const __bf16* ga0 = A  + (size_t)(bm + (c0>>2))*lda + ((c0&3)<<3);
    const __bf16* ga1 = A  + (size_t)(bm + (c1>>2))*lda + ((c1&3)<<3);
    const __bf16* gb0 = BT + (size_t)(bn + (c0>>2))*ldb + ((c0&3)<<3);
    const __bf16* gb1 = BT + (size_t)(bn + (c1>>2))*ldb + ((c1&3)<<3);
    auto* lA = (__attribute__((address_space(3))) __bf16*)&As[0][0];
    auto* lB = (__attribute__((address_space(3))) __bf16*)&Bs[0][0];
    auto* lA0 = (__attribute__((address_space(3))) void*)(lA + (size_t)(wid*64)*8);
    auto* lA1 = (__attribute__((address_space(3))) void*)(lA + (size_t)(256 + wid*64)*8);
    auto* lB0 = (__attribute__((address_space(3))) void*)(lB + (size_t)(wid*64)*8);
    auto* lB1 = (__attribute__((address_space(3))) void*)(lB + (size_t)(256 + wid*64)*8);

    const int r  = lane & 15;
    const int kb = lane >> 4;
    const int arow = wm*64, brow = wn*64;

    for (int k0 = 0; k0 < K; k0 += 32) {
        __builtin_amdgcn_global_load_lds((const __attribute__((address_space(1))) void*)ga0, lA0, 16, 0, 0);
        __builtin_amdgcn_global_load_lds((const __attribute__((address_space(1))) void*)ga1, lA1, 16, 0, 0);
        __builtin_amdgcn_global_load_lds((const __attribute__((address_space(1))) void*)gb0, lB0, 16, 0, 0);
        __builtin_amdgcn_global_load_lds((const __attribute__((address_space(1))) void*)gb1, lB1, 16, 0, 0);
        ga0 += 32; ga1 += 32; gb0 += 32; gb1 += 32;
        __syncthreads();
        bf16x8 af[4], bfr[4];
        #pragma unroll
        for (int m=0;m<4;m++) af[m]  = *(const bf16x8*)&As[arow + m*16 + r][kb*8];
        #pragma unroll
        for (int n=0;n<4;n++) bfr[n] = *(const bf16x8*)&Bs[brow + n*16 + r][kb*8];
        #pragma unroll
        for (int m=0;m<4;m++)
            #pragma unroll
            for (int n=0;n<4;n++)
                acc[m][n] = __builtin_amdgcn_mfma_f32_16x16x32_bf16(af[m], bfr[n], acc[m][n], 0, 0, 0);
        __syncthreads();
    }

    const int crow = (lane >> 4) * 4;
    const int ccol = lane & 15;
    #pragma unroll
    for (int m=0;m<4;m++) {
        #pragma unroll
        for (int n=0;n<4;n++) {
            const int gn = bn + wn*64 + n*16 + ccol;
            #pragma unroll
            for (int q=0;q<4;q++) {
                const int gm = bm + wm*64 + m*16 + crow + q;
                float v = acc[m][n][q] * alpha;
                if (EM==MM_BIAS || EM==MM_BIAS_B16 || EM==MM_RELU_B16) v += aux1[gn];
                if (EM==MM_RELU_B16) v = fmaxf(v, 0.f);
                if (EM==MM_SIGSP_B16) {
                    v = 1.f/(1.f + __expf(-v));
                    v *= __expf(aux2[(size_t)(gm >> 1)*(size_t)N + gn] * (-1.f/LS2));
                }
                if (EM==MM_DIST) {
                    float d2 = fmaxf(aux2[gm] + aux2[gn] - 2.f*v, 0.f);
                    v = __expf(aux1[gn] - sqrtf(d2));
                }
                const size_t ci = (size_t)gm*ldc + gn;
                if (EM==MM_NONE || EM==MM_BIAS) C[ci] = v;
                else Cb[ci] = (__bf16)v;
            }
        }
    }
}

// ========== split-K MFMA GEMM: bf16 partials to P[ks][M][N] ================
__launch_bounds__(256)
__global__ void mgemm_sk(const __bf16* __restrict__ A, int lda,
                         const __bf16* __restrict__ BT, int ldb,
                         __bf16* __restrict__ P, int M, int N, int KC,
                         const int* __restrict__ flag)
{
    if (flag && *flag == 0) return;
    __shared__ __align__(16) __bf16 As[128][32];
    __shared__ __align__(16) __bf16 Bs[128][32];
    const int tid  = threadIdx.x;
    const int lane = tid & 63;
    const int wid  = tid >> 6;
    const int wm = wid >> 1, wn = wid & 1;
    const int nwg  = gridDim.x * gridDim.y;
    const int wg   = xcd_swz(blockIdx.y * gridDim.x + blockIdx.x, nwg);
    const int bm = (wg / gridDim.x) * 128, bn = (wg % gridDim.x) * 128;
    const size_t koff = (size_t)blockIdx.z * KC;

    f32x4 acc[4][4];
    #pragma unroll
    for (int m=0;m<4;m++)
        #pragma unroll
        for (int n=0;n<4;n++) acc[m][n] = (f32x4){0.f,0.f,0.f,0.f};

    const int c0 = wid*64 + lane, c1 = c0 + 256;
    const __bf16* ga0 = A  + (size_t)(bm + (c0>>2))*lda + koff + ((c0&3)<<3);
    const __bf16* ga1 = A  + (size_t)(bm + (c1>>2))*lda + koff + ((c1&3)<<3);
    const __bf16* gb0 = BT + (size_t)(bn + (c0>>2))*ldb + koff + ((c0&3)<<3);
    const __bf16* gb1 = BT + (size_t)(bn + (c1>>2))*ldb + koff + ((c1&3)<<3);
    auto* lA = (__attribute__((address_space(3))) __bf16*)&As[0][0];
    auto* lB = (__attribute__((address_space(3))) __bf16*)&Bs[0][0];
    auto* lA0 = (__attribute__((address_space(3))) void*)(lA + (size_t)(wid*64)*8);
    auto* lA1 = (__attribute__((address_space(3))) void*)(lA + (size_t)(256 + wid*64)*8);
    auto* lB0 = (__attribute__((address_space(3))) void*)(lB + (size_t)(wid*64)*8);
    auto* lB1 = (__attribute__((address_space(3))) void*)(lB + (size_t)(256 + wid*64)*8);

    const int r  = lane & 15;
    const int kb = lane >> 4;
    const int arow = wm*64, brow = wn*64;

    for (int k0 = 0; k0 < KC; k0 += 32) {
        __builtin_amdgcn_global_load_lds((const __attribute__((address_space(1))) void*)ga0, lA0, 16, 0, 0);
        __builtin_amdgcn_global_load_lds((const __attribute__((address_space(1))) void*)ga1, lA1, 16, 0, 0);
        __builtin_amdgcn_global_load_lds((const __attribute__((address_space(1))) void*)gb0, lB0, 16, 0, 0);
        __builtin_amdgcn_global_load_lds((const __attribute__((address_space(1))) void*)gb1, lB1, 16, 0, 0);
        ga0 += 32; ga1 += 32; gb0 += 32; gb1 += 32;
        __syncthreads();
        bf16x8 af[4], bfr[4];
        #pragma unroll
        for (int m=0;m<4;m++) af[m]  = *(const bf16x8*)&As[arow + m*16 + r][kb*8];
        #pragma unroll
        for (int n=0;n<4;n++) bfr[n] = *(const bf16x8*)&Bs[brow + n*16 + r][kb*8];
        #pragma unroll
        for (int m=0;m<4;m++)
            #pragma unroll
            for (int n=0;n<4;n++)
                acc[m][n] = __builtin_amdgcn_mfma_f32_16x16x32_bf16(af[m], bfr[n], acc[m][n], 0, 0, 0);
        __syncthreads();
    }

    __bf16* Pz = P + (size_t)blockIdx.z * M * N;
    const int crow = (lane >> 4) * 4;
    const int ccol = lane & 15;
    #pragma unroll
    for (int m=0;m<4;m++)
        #pragma unroll
        for (int n=0;n<4;n++) {
            const int gn = bn + wn*64 + n*16 + ccol;
            #pragma unroll
            for (int q=0;q<4;q++) {
                const int gm = bm + wm*64 + m*16 + crow + q;
                Pz[(size_t)gm*N + gn] = (__bf16)acc[m][n][q];
            }
        }
}

// ========== 256x256 deep-pipelined split-K GEMM (counted vmcnt) ============
// r14 schedule: only pair-end certify (vmcnt(N) then s_barrier).
__launch_bounds__(512, 1)
__global__ void mg256_sk(const __bf16* __restrict__ A, int lda,
                         const __bf16* __restrict__ BT, int ldb,
                         __bf16* __restrict__ P, int M, int N, int KC,
                         const int* __restrict__ flag)
{
    if (flag && *flag == 0) return;
    extern __shared__ __align__(16) __bf16 lds[];
    auto* L3 = (__attribute__((address_space(3))) __bf16*)lds;
    const int tid  = threadIdx.x;
    const int lane = tid & 63, w = tid >> 6;
    const int wm = w >> 2, wn = w & 3;
    const int nwg = gridDim.x * gridDim.y;
    const int wg  = xcd_swz(blockIdx.y * gridDim.x + blockIdx.x, nwg);
    const int bm = (wg / gridDim.x) * 256, bn = (wg % gridDim.x) * 256;
    const size_t koff = (size_t)blockIdx.z * KC;
    const int NT = KC / 64;
    const int r = lane & 15, kb = lane >> 4;
    const int rdk = (kb ^ ((r ^ (r >> 2)) & 3)) * 8;

    f32x4 acc[8][4];
    #pragma unroll
    for (int m=0;m<8;m++)
        #pragma unroll
        for (int n=0;n<4;n++) acc[m][n] = (f32x4){0.f,0.f,0.f,0.f};

    auto stage = [&](const __bf16* src, int ld, int brc, int kt, int s, int region) {
        #pragma unroll
        for (int j = 0; j < 2; ++j) {
            int c = j*512 + tid;
            int kc = (c & 3) ^ (((c >> 2) ^ (c >> 4)) & 3);
            const __bf16* g = src + (size_t)(brc + (c>>2))*ld + koff + (size_t)kt*64 + s*32 + (kc<<3);
            __builtin_amdgcn_global_load_lds(
                (const __attribute__((address_space(1))) void*)g,
                (__attribute__((address_space(3))) void*)(L3 + region + (j*512 + w*64)*8),
                16, 0, 0);
        }
    };
    auto ldsA = [&](int d, int s, int m) -> bf16x8 {
        return *(const bf16x8*)&lds[(d*2+s)*8192 + (wm*128 + m*16 + r)*32 + rdk];
    };
    auto ldsB = [&](int d, int s, int n) -> bf16x8 {
        return *(const bf16x8*)&lds[32768 + (d*2+s)*8192 + (wn*64 + n*16 + r)*32 + rdk];
    };

    stage(A,  lda, bm, 0, 0, 0*8192);
    stage(BT, ldb, bn, 0, 0, 32768 + 0*8192);
    stage(A,  lda, bm, 0, 1, 1*8192);
    stage(BT, ldb, bn, 0, 1, 32768 + 1*8192);
    stage(A,  lda, bm, 1, 0, 2*8192);
    stage(BT, ldb, bn, 1, 0, 32768 + 2*8192);
    asm volatile("s_waitcnt vmcnt(8)" ::: "memory");
    __builtin_amdgcn_s_barrier();

    for (int i = 0; i < NT/2; ++i) {
        const int t1 = 2*i+1, t2 = 2*i+2, t3 = 2*i+3;
        bf16x8 bf[4], af[4];

#define MG256_MFMA(MB) \
        __builtin_amdgcn_s_setprio(1); \
        _Pragma("unroll") \
        for (int mi=0; mi<4; ++mi) \
            _Pragma("unroll") \
            for (int n=0; n<4; ++n) \
                acc[MB+mi][n] = __builtin_amdgcn_mfma_f32_16x16x32_bf16(af[mi], bf[n], acc[MB+mi][n], 0, 0, 0); \
        __builtin_amdgcn_s_setprio(0);

        // ---- pair 0 ----
        #pragma unroll
        for (int n=0;n<4;n++)  bf[n] = ldsB(0,0,n);
        #pragma unroll
        for (int mi=0;mi<4;mi++) af[mi] = ldsA(0,0,mi);
        stage(A, lda, bm, t1, 1, 3*8192);
        MG256_MFMA(0)
        #pragma unroll
        for (int mi=0;mi<4;mi++) af[mi] = ldsA(0,0,4+mi);
        stage(BT, ldb, bn, t1, 1, 32768 + 3*8192);
        MG256_MFMA(4)
        asm volatile("s_waitcnt vmcnt(8)" ::: "memory");
        __builtin_amdgcn_s_barrier();

        // ---- pair 1 ----
        #pragma unroll
        for (int n=0;n<4;n++)  bf[n] = ldsB(0,1,n);
        #pragma unroll
        for (int mi=0;mi<4;mi++) af[mi] = ldsA(0,1,mi);
        if (t2 < NT) stage(A, lda, bm, t2, 0, 0*8192);
        MG256_MFMA(0)
        #pragma unroll
        for (int mi=0;mi<4;mi++) af[mi] = ldsA(0,1,4+mi);
        if (t2 < NT) stage(BT, ldb, bn, t2, 0, 32768 + 0*8192);
        MG256_MFMA(4)
        if (t2 < NT) { asm volatile("s_waitcnt vmcnt(8)" ::: "memory"); }
        else         { asm volatile("s_waitcnt vmcnt(4)" ::: "memory"); }
        __builtin_amdgcn_s_barrier();

        // ---- pair 2 ----
        #pragma unroll
        for (int n=0;n<4;n++)  bf[n] = ldsB(1,0,n);
        #pragma unroll
        for (int mi=0;mi<4;mi++) af[mi] = ldsA(1,0,mi);
        if (t2 < NT) stage(A, lda, bm, t2, 1, 1*8192);
        MG256_MFMA(0)
        #pragma unroll
        for (int mi=0;mi<4;mi++) af[mi] = ldsA(1,0,4+mi);
        if (t2 < NT) stage(BT, ldb, bn, t2, 1, 32768 + 1*8192);
        MG256_MFMA(4)
        if (t2 < NT) { asm volatile("s_waitcnt vmcnt(8)" ::: "memory"); }
        else         { asm volatile("s_waitcnt vmcnt(0)" ::: "memory"); }
        __builtin_amdgcn_s_barrier();

        // ---- pair 3 ----
        #pragma unroll
        for (int n=0;n<4;n++)  bf[n] = ldsB(1,1,n);
        #pragma unroll
        for (int mi=0;mi<4;mi++) af[mi] = ldsA(1,1,mi);
        if (t3 < NT) stage(A, lda, bm, t3, 0, 2*8192);
        MG256_MFMA(0)
        #pragma unroll
        for (int mi=0;mi<4;mi++) af[mi] = ldsA(1,1,4+mi);
        if (t3 < NT) stage(BT, ldb, bn, t3, 0, 32768 + 2*8192);
        MG256_MFMA(4)
        if (t3 < NT) { asm volatile("s_waitcnt vmcnt(8)" ::: "memory"); }
        __builtin_amdgcn_s_barrier();
#undef MG256_MFMA
    }
    asm volatile("s_waitcnt vmcnt(0)" ::: "memory");

    __bf16* Pz = P + (size_t)blockIdx.z * M * N;
    const int crow = (lane >> 4) * 4;
    const int ccol = lane & 15;
    #pragma unroll
    for (int m=0;m<8;m++)
        #pragma unroll
        for (int n=0;n<4;n++) {
            const int gn = bn + wn*64 + n*16 + ccol;
            #pragma unroll
            for (int q=0;q<4;q++) {
                const int gm = bm + wm*128 + m*16 + crow + q;
                Pz[(size_t)gm*N + gn] = (__bf16)acc[m][n][q];
            }
        }
}

// ========== split-K reduce (bf16 partials, column-sliced) ==================
enum { R_F32=0, R_B16LD, R_ACCG, R_RELU_B16, R_BRB16, R_TANH, R_BOTH, R_RS,
       R_BIAS16, R_BIASF, R_CIH, R_TEMB, R_QKVE };

template<int RE>
__launch_bounds__(256)
__global__ void redk_k(const __bf16* __restrict__ P, int M, int N, int ldp, int pcoff,
                       int KS,
                       const float* __restrict__ bias,
                       const float* __restrict__ res, int ldres,
                       float* __restrict__ C, __bf16* __restrict__ Cb,
                       int ldout, int coff,
                       const int* __restrict__ flag, float alpha)
{
    if (flag && *flag == 0) return;
    int i = blockIdx.x*256 + threadIdx.x;
    int total = (M*N) >> 2;
    if (i >= total) return;
    int row = i / (N >> 2);
    int c4  = (i - row*(N >> 2)) << 2;
    f32x4 s = {0.f,0.f,0.f,0.f};
    for (int ks = 0; ks < KS; ++ks) {
        bf16x4 t = *(const bf16x4*)(P + ((size_t)ks*M + row)*ldp + pcoff + c4);
        s[0] += (float)t[0]; s[1] += (float)t[1];
        s[2] += (float)t[2]; s[3] += (float)t[3];
    }
    #pragma unroll
    for (int j=0;j<4;j++) {
        int col = c4 + j;
        float v = s[j];
        if (RE==R_RELU_B16) v = fmaxf(v + bias[col], 0.f);
        if (RE==R_BRB16)    v = v + bias[col] + res[(size_t)row*ldres + col];
        if (RE==R_TANH)     v = tanhf(v + bias[col]);
        if (RE==R_BOTH || RE==R_BIAS16 || RE==R_BIASF) v = v + bias[col];
        if (RE==R_QKVE)   { v = v + bias[col]; if (col < 128) v *= QSCALE; }
        if (RE==R_RS)       v = v * res[row];
        size_t o = (size_t)row*ldout + coff + col;
        if (RE==R_CIH)  o = (size_t)(row >> 1)*ldout + (size_t)(row & 1)*GG + col;
        if (RE==R_TEMB) o = ((size_t)row*2 + (col >> 7))*DM + (col & 127);
        if (RE==R_F32 || RE==R_TANH || RE==R_BIASF) C[o] = v;
        if (RE==R_BOTH) { C[o] = v; Cb[o] = (__bf16)v; }
        if (RE==R_RS)   { C[o] = v; Cb[o] = (__bf16)v; }
        if (RE==R_B16LD || RE==R_RELU_B16 || RE==R_BIAS16 || RE==R_CIH || RE==R_TEMB ||
            RE==R_QKVE || RE==R_BRB16) Cb[o] = (__bf16)v;
        if (RE==R_ACCG) C[o] += v * alpha;
    }
}

// ========== fused split-K reduce + bias + residual + LayerNorm (+rownorm) ==
__launch_bounds__(64)
__global__ void redln_k(const __bf16* __restrict__ P, int KS,
                        const float* __restrict__ bias,
                        float* __restrict__ h, __bf16* __restrict__ hb,
                        const float* __restrict__ g, const float* __restrict__ b,
                        float* __restrict__ sq)
{
    int row = blockIdx.x, lane = threadIdx.x;
    float v0 = bias[lane], v1 = bias[lane + 64];
    for (int ks = 0; ks < KS; ++ks) {
        v0 += (float)P[((size_t)ks*NC + row)*DM + lane];
        v1 += (float)P[((size_t)ks*NC + row)*DM + lane + 64];
    }
    float x0 = h[row*DM + lane]      + v0;
    float x1 = h[row*DM + lane + 64] + v1;
    float s = x0 + x1, ss = x0*x0 + x1*x1;
    #pragma unroll
    for (int o=32;o>0;o>>=1) { s += __shfl_down(s, o); ss += __shfl_down(ss, o); }
    s = __shfl(s, 0); ss = __shfl(ss, 0);
    float mean = s * (1.f/128.f);
    float var  = ss * (1.f/128.f) - mean*mean;
    float inv  = rsqrtf(var + 1e-5f);
    float y0 = g[lane]      * (x0 - mean) * inv + b[lane];
    float y1 = g[lane + 64] * (x1 - mean) * inv + b[lane + 64];
    h[row*DM + lane]       = y0;  h[row*DM + lane + 64]  = y1;
    hb[row*DM + lane]      = (__bf16)y0;
    hb[row*DM + lane + 64] = (__bf16)y1;
    if (sq) {
        float t = y0*y0 + y1*y1;
        #pragma unroll
        for (int o=32;o>0;o>>=1) t += __shfl_down(t, o);
        if (lane == 0) sq[row] = t;
    }
}

// ================= flash attention, KV-split partials, no-max softmax =======
__launch_bounds__(256)
__global__ void flashp_k(const __bf16* __restrict__ Q, const __bf16* __restrict__ Kb,
                         int ldqk, const __bf16* __restrict__ VT, int ldv,
                         __bf16* __restrict__ Op, float* __restrict__ lp)
{
    __shared__ __align__(16) __bf16 Plds[4][64][68];
    const int lane = threadIdx.x & 63, w = threadIdx.x >> 6;
    const int hd = blockIdx.y, sp = blockIdx.z;
    const int q0 = blockIdx.x * 256 + w * 64;
    const int c  = lane & 15, kb = lane >> 4;

    bf16x8 aq[4];
    #pragma unroll
    for (int qs=0;qs<4;qs++)
        aq[qs] = *(const bf16x8*)&Q[(size_t)(q0 + qs*16 + c)*ldqk + hd*HDIM + kb*8];
    bf16x8 ones;
    #pragma unroll
    for (int j=0;j<8;j++) ones[j] = (__bf16)1.0f;

    f32x4 oacc[4][2];
    f32x4 lacc[4];
    #pragma unroll
    for (int qs=0;qs<4;qs++) {
        oacc[qs][0] = (f32x4){0,0,0,0}; oacc[qs][1] = (f32x4){0,0,0,0};
        lacc[qs] = (f32x4){0,0,0,0};
    }

    const int kv0 = sp * (NC/NSF), kv1 = kv0 + NC/NSF;
    for (int kv = kv0; kv < kv1; kv += 64) {
        bf16x8 bk[4];
        #pragma unroll
        for (int n=0;n<4;n++)
            bk[n] = *(const bf16x8*)&Kb[(size_t)(kv + n*16 + c)*ldqk + hd*HDIM + kb*8];
        bf16x8 bv[2][2];
        #pragma unroll
        for (int ks=0;ks<2;ks++)
            #pragma unroll
            for (int n2=0;n2<2;n2++)
                bv[ks][n2] = *(const bf16x8*)&VT[(size_t)(hd*HDIM + n2*16 + c)*ldv + kv + ks*32 + kb*8];
        #pragma unroll
        for (int qs=0;qs<4;qs++) {
            f32x4 s[4];
            #pragma unroll
            for (int n=0;n<4;n++)
                s[n] = __builtin_amdgcn_mfma_f32_16x16x32_bf16(aq[qs], bk[n], (f32x4){0,0,0,0}, 0, 0, 0);
            #pragma unroll
            for (int n=0;n<4;n++)
                #pragma unroll
                for (int q=0;q<4;q++)
                    Plds[w][qs*16 + kb*4 + q][n*16 + c] = (__bf16)__expf(s[n][q]);
        }
        #pragma unroll
        for (int qs=0;qs<4;qs++)
            #pragma unroll
            for (int ks=0;ks<2;ks++) {
                bf16x8 ap = *(const bf16x8*)&Plds[w][qs*16 + c][ks*32 + kb*8];
                #pragma unroll
                for (int n2=0;n2<2;n2++)
                    oacc[qs][n2] = __builtin_amdgcn_mfma_f32_16x16x32_bf16(ap, bv[ks][n2], oacc[qs][n2], 0, 0, 0);
                lacc[qs] = __builtin_amdgcn_mfma_f32_16x16x32_bf16(ap, ones, lacc[qs], 0, 0, 0);
            }
    }
    __bf16* Oz = Op + (size_t)sp * NC * DM;
    #pragma unroll
    for (int qs=0;qs<4;qs++)
        #pragma unroll
        for (int n2=0;n2<2;n2++)
            #pragma unroll
            for (int q=0;q<4;q++)
                Oz[(size_t)(q0 + qs*16 + kb*4 + q)*DM + hd*HDIM + n2*16 + c] = (__bf16)oacc[qs][n2][q];
    if (c == 0) {
        #pragma unroll
        for (int qs=0;qs<4;qs++)
            #pragma unroll
            for (int q=0;q<4;q++)
                lp[((size_t)sp*HH + hd)*NC + q0 + qs*16 + kb*4 + q] = lacc[qs][q];
    }
}

// merge NSF partials -> O bf16 [NC][DM]
__launch_bounds__(256)
__global__ void flashmerge_k(const __bf16* __restrict__ Op, const float* __restrict__ lp,
                             __bf16* __restrict__ O)
{
    int idx = blockIdx.x*256 + threadIdx.x;
    int row = idx >> 7, col = idx & 127, hd = col >> 5;
    float L = 0.f, acc = 0.f;
    #pragma unroll
    for (int s=0;s<NSF;s++) {
        L   += lp[((size_t)s*HH + hd)*NC + row];
        acc += (float)Op[(size_t)s*NC*DM + idx];
    }
    O[idx] = (__bf16)(acc / L);
}

// ================= megaprep: all weight packs in ONE launch =================
__device__ __forceinline__ void tconv32(float (*tile)[33],
                                        const float* __restrict__ in,
                                        __bf16* __restrict__ out,
                                        int R, int C, int ldout, int coff, int t)
{
    int tx = threadIdx.x & 31, ty = threadIdx.x >> 5;
    int bx = t % (C/32), by = t / (C/32);
    int bc = bx*32, br = by*32;
    #pragma unroll
    for (int i=0;i<4;i++)
        tile[ty + 8*i][tx] = in[(size_t)(br + ty + 8*i)*C + bc + tx];
    __syncthreads();
    #pragma unroll
    for (int i=0;i<4;i++)
        out[(size_t)(bc + ty + 8*i)*ldout + coff + br + tx] = (__bf16)tile[tx][ty + 8*i];
}

__launch_bounds__(256)
__global__ void megaprep_k(const float* __restrict__ dn_W1, const float* __restrict__ dn_W2,
                           const float* __restrict__ e_Win, const float* __restrict__ q_W1,
                           const float* __restrict__ q_b1,
                           const float* __restrict__ Wq, const float* __restrict__ Wk,
                           const float* __restrict__ Wv,
                           const float* __restrict__ bq, const float* __restrict__ bk,
                           const float* __restrict__ bv,
                           const float* __restrict__ Wo, const float* __restrict__ f_W1,
                           const float* __restrict__ f_W2,
                           const float* __restrict__ ci_T, const float* __restrict__ ci_G,
                           const float* __restrict__ raw,
                           __bf16* __restrict__ dnW1T, __bf16* __restrict__ dnW2T,
                           __bf16* __restrict__ eWinT, __bf16* __restrict__ qW1pT,
                           float* __restrict__ qb1p,
                           __bf16* __restrict__ Wqkv, float* __restrict__ bqkv,
                           __bf16* __restrict__ WoT, __bf16* __restrict__ fW1T,
                           __bf16* __restrict__ fW2T, __bf16* __restrict__ ciTT,
                           __bf16* __restrict__ ciGbigT, __bf16* __restrict__ rawB,
                           const int* __restrict__ interact)
{
    __shared__ float tile[32][33];
    int t = blockIdx.x;
    if (t < 512) { tconv32(tile, dn_W1, dnW1T, GG, FF, GG, 0, t); return; }
    t -= 512;
    if (t < 512) { tconv32(tile, dn_W2, dnW2T, FF, GG, FF, 0, t); return; }
    t -= 512;
    if (t < 128) { tconv32(tile, e_Win, eWinT, GG, DM, GG, 0, t); return; }
    t -= 128;
    if (t < 512) {
        int idx = t*256 + threadIdx.x;
        int k = idx & 1023, j = idx >> 10;
        qW1pT[(size_t)j*GG + k] = (j < 64) ? (__bf16)q_W1[(size_t)k*64 + j] : (__bf16)0.f;
        return;
    }
    t -= 512;
    if (t < 1) {
        if (threadIdx.x < 128) qb1p[threadIdx.x] = (threadIdx.x < 64) ? q_b1[threadIdx.x] : 0.f;
        return;
    }
    t -= 1;
    if (t < 384) {
        int l = t / 192;
        int i = (t % 192)*256 + threadIdx.x;
        int n = i >> 7, k = i & 127;
        const float* W = (n < 128) ? Wq : (n < 256 ? Wk : Wv);
        Wqkv[(size_t)l*384*128 + i] = (__bf16)W[(size_t)l*DM*DM + (size_t)k*DM + (n & 127)];
        if (i < 384) {
            const float* b = (i < 128) ? bq : (i < 256 ? bk : bv);
            bqkv[l*384 + i] = b[l*DM + (i & 127)];
        }
        return;
    }
    t -= 384;
    if (t < 32) { int l = t/16; tconv32(tile, Wo + (size_t)l*DM*DM, WoT + (size_t)l*DM*DM, DM, DM, DM, 0, t%16); return; }
    t -= 32;
    if (t < 128) { int l = t/64; tconv32(tile, f_W1 + (size_t)l*DM*FF, fW1T + (size_t)l*FF*DM, DM, FF, DM, 0, t%64); return; }
    t -= 128;
    if (t < 128) { int l = t/64; tconv32(tile, f_W2 + (size_t)l*FF*DM, fW2T + (size_t)l*DM*FF, FF, DM, FF, 0, t%64); return; }
    t -= 128;
    if (t < 32) {
        if (*interact) { int l = t/16; tconv32(tile, ci_T + (size_t)l*DM*DM, ciTT + (size_t)l*DM*DM, DM, DM, DM, 0, t%16); }
        return;
    }
    t -= 32;
    if (t < 2048) {
        if (*interact) { int hh = t/1024; tconv32(tile, ci_G + (size_t)hh*GG*GG, ciGbigT, GG, GG, 2*GG, hh*GG, t%1024); }
        return;
    }
    t -= 2048;
    {
        int i = t*256 + threadIdx.x;
        float4 v = ((const float4*)raw)[i];
        bf16x4 o = {(__bf16)v.x, (__bf16)v.y, (__bf16)v.z, (__bf16)v.w};
        ((bf16x4*)rawB)[i] = o;
    }
}

// ================= small kernels =================
__global__ void qualify2_k(const float* __restrict__ Tq, const float* __restrict__ w,
                           const float* __restrict__ b2, float* __restrict__ quality)
{
    int row = blockIdx.x, lane = threadIdx.x;
    float v = Tq[row*128 + lane] * w[lane];
    #pragma unroll
    for (int o=32;o>0;o>>=1) v += __shfl_down(v, o);
    if (lane == 0) quality[row] = v + b2[0];
}

__launch_bounds__(256)
__global__ void rowsum16_k(const __bf16* __restrict__ P, float* __restrict__ rinv)
{
    __shared__ float sl[4];
    size_t row = blockIdx.x;
    const __bf16* p = P + row * (size_t)NC;
    int tid = threadIdx.x;
    float sum = 0.f;
    for (int j = tid*8; j < NC; j += 256*8) {
        bf16x8 v = *(const bf16x8*)&p[j];
        #pragma unroll
        for (int k=0;k<8;k++) sum += (float)v[k];
    }
    #pragma unroll
    for (int o=32;o>0;o>>=1) sum += __shfl_down(sum, o);
    if ((tid & 63) == 0) sl[tid >> 6] = sum;
    __syncthreads();
    if (tid == 0) rinv[row] = 1.f / (sl[0] + sl[1] + sl[2] + sl[3]);
}

__global__ void tconv16_k(const __bf16* __restrict__ in, int ldin, int coff,
                          __bf16* __restrict__ out, int ldout)
{
    __shared__ __bf16 tile[32][33];
    int bc = blockIdx.x * 32, br = blockIdx.y * 32;
    int tx = threadIdx.x & 31, ty = threadIdx.x >> 5;
    #pragma unroll
    for (int i=0;i<4;i++)
        tile[ty + 8*i][tx] = in[(size_t)(br + ty + 8*i)*ldin + coff + bc + tx];
    __syncthreads();
    #pragma unroll
    for (int i=0;i<4;i++)
        out[(size_t)(bc + ty + 8*i)*ldout + br + tx] = tile[tx][ty + 8*i];
}

// ================= launchers =================
static void mg(int em, const __bf16* A, int lda, const __bf16* BT, int ldb,
               const float* aux1, float* C, __bf16* Cb, int ldc,
               int M, int N, int K, float alpha,
               const float* aux2, const int* flag, hipStream_t s)
{
    dim3 grid(N/128, M/128), block(256);
#define MGL(E) mgemm_k<E><<<grid,block,0,s>>>(A,lda,BT,ldb,aux1,C,Cb,ldc,M,N,K,alpha,aux2,flag)
    switch (em) {
        case MM_NONE:      MGL(MM_NONE);      break;
        case MM_BIAS:      MGL(MM_BIAS);      break;
        case MM_BIAS_B16:  MGL(MM_BIAS_B16);  break;
        case MM_RELU_B16:  MGL(MM_RELU_B16);  break;
        case MM_B16:       MGL(MM_B16);       break;
        case MM_SIGSP_B16: MGL(MM_SIGSP_B16); break;
        case MM_DIST:      MGL(MM_DIST);      break;
    }
#undef MGL
}

static void sk(const __bf16* A, int lda, const __bf16* BT, int ldb,
               __bf16* P, int M, int N, int K, int KS, const int* flag, hipStream_t s)
{
    dim3 grid(N/128, M/128, KS), block(256);
    mgemm_sk<<<grid, block, 0, s>>>(A, lda, BT, ldb, P, M, N, K/KS, flag);
}

static void sk256(const __bf16* A, int lda, const __bf16* BT, int ldb,
                  __bf16* P, int M, int N, int K, int KS, const int* flag, hipStream_t s)
{
    dim3 grid(N/256, M/256, KS), block(512);
    mg256_sk<<<grid, block, 131072, s>>>(A, lda, BT, ldb, P, M, N, K/KS, flag);
}

static void red(int re, const __bf16* P, int M, int N, int ldp, int pcoff, int KS,
                const float* bias, const float* res, int ldres,
                float* C, __bf16* Cb, int ldout, int coff,
                const int* flag, float alpha, hipStream_t s)
{
    int blocks = (M*N/4 + 255) / 256;
#define RDL(E) redk_k<E><<<blocks,256,0,s>>>(P,M,N,ldp,pcoff,KS,bias,res,ldres,C,Cb,ldout,coff,flag,alpha)
    switch (re) {
        case R_F32:      RDL(R_F32);      break;
        case R_B16LD:    RDL(R_B16LD);    break;
        case R_ACCG:     RDL(R_ACCG);     break;
        case R_RELU_B16: RDL(R_RELU_B16); break;
        case R_BRB16:    RDL(R_BRB16);    break;
        case R_TANH:     RDL(R_TANH);     break;
        case R_BOTH:     RDL(R_BOTH);     break;
        case R_RS:       RDL(R_RS);       break;
        case R_BIAS16:   RDL(R_BIAS16);   break;
        case R_BIASF:    RDL(R_BIASF);    break;
        case R_CIH:      RDL(R_CIH);      break;
        case R_TEMB:     RDL(R_TEMB);     break;
        case R_QKVE:     RDL(R_QKVE);     break;
    }
#undef RDL
}

extern "C" void kernel_launch(void* const* d_in, const int* in_sizes, int n_in,
                              void* d_out, int out_size, void* d_ws, size_t ws_size,
                              hipStream_t stream)
{
    const float* raw   = (const float*)d_in[0];
    const float* spd   = (const float*)d_in[1];
    const float* dn_W1 = (const float*)d_in[2];
    const float* dn_b1 = (const float*)d_in[3];
    const float* dn_W2 = (const float*)d_in[4];
    const float* dn_b2 = (const float*)d_in[5];
    const float* q_W1  = (const float*)d_in[6];
    const float* q_b1  = (const float*)d_in[7];
    const float* q_W2  = (const float*)d_in[8];
    const float* q_b2  = (const float*)d_in[9];
    const float* e_Win = (const float*)d_in[10];
    const float* e_bin = (const float*)d_in[11];
    const float* Wq    = (const float*)d_in[12];
    const float* Wk    = (const float*)d_in[13];
    const float* Wv    = (const float*)d_in[14];
    const float* Wo    = (const float*)d_in[15];
    const float* bq    = (const float*)d_in[16];
    const float* bk    = (const float*)d_in[17];
    const float* bv    = (const float*)d_in[18];
    const float* bo    = (const float*)d_in[19];
    const float* ln1_g = (const float*)d_in[20];
    const float* ln1_b = (const float*)d_in[21];
    const float* ln2_g = (const float*)d_in[22];
    const float* ln2_b = (const float*)d_in[23];
    const float* f_W1  = (const float*)d_in[24];
    const float* f_b1  = (const float*)d_in[25];
    const float* f_W2  = (const float*)d_in[26];
    const float* f_b2  = (const float*)d_in[27];
    const float* ci_T  = (const float*)d_in[28];
    const float* ci_G  = (const float*)d_in[29];
    const int*   interact = (const int*)d_in[30];
    (void)in_sizes; (void)n_in; (void)ws_size; (void)out_size;

    (void)hipFuncSetAttribute((const void*)mg256_sk,
                              hipFuncAttributeMaxDynamicSharedMemorySize, 131072);

    float* out = (float*)d_out;
    float* ws = (float*)d_ws;
    size_t off = 0;
    auto af32 = [&](size_t n) { float* p = ws + off; off += n; return p; };
    auto ab16 = [&](size_t n) { __bf16* p = (__bf16*)(ws + off); off += (n + 1) / 2; return p; };

    float*  S        = af32((size_t)NC * NC);
    __bf16* simB     = ab16((size_t)NC * NC);
    __bf16* ciS2     = ab16((size_t)NC * NC);
    __bf16* denB     = ab16((size_t)NC * GG);
    __bf16* smoB     = ab16((size_t)NC * GG);
    __bf16* T1b      = ab16((size_t)NC * FF);
    float*  Tq       = af32((size_t)NC * 128);
    float*  quality  = af32(NC);
    float*  rowinv   = af32(NC);
    float*  h        = af32((size_t)NC * DM);
    __bf16* hb       = ab16((size_t)NC * DM);
    __bf16* qkvB     = ab16((size_t)NC * 384);
    __bf16* vbT      = ab16((size_t)DM * LDV);
    __bf16* obB      = ab16((size_t)NC * DM);
    __bf16* rawB     = ab16((size_t)NC * GG);
    __bf16* denT     = ab16((size_t)GG * NC);
    __bf16* smoT     = ab16((size_t)GG * NC);
    __bf16* Ubig     = ab16((size_t)NC * 2*GG);
    __bf16* TembBig  = ab16((size_t)NHCI * NC * DM);
    float*  sqbuf    = af32(NC);
    __bf16* dnW1T    = ab16((size_t)768 * GG);          // Wcat = [dnW1T;qW1pT;eWinT]
    __bf16* qW1pT    = dnW1T + (size_t)512 * GG;
    __bf16* eWinT    = dnW1T + (size_t)640 * GG;
    __bf16* dnW2T    = ab16((size_t)GG * FF);
    float*  qb1p     = af32(128);
    __bf16* Wqkv     = ab16((size_t)LL * 384 * DM);
    float*  bqkv     = af32((size_t)LL * 384);
    __bf16* WoT      = ab16((size_t)LL * DM * DM);
    __bf16* fW1T     = ab16((size_t)LL * FF * DM);
    __bf16* fW2T     = ab16((size_t)LL * DM * FF);
    __bf16* ciTT     = ab16((size_t)NHCI * DM * DM);
    __bf16* ciGbigT  = ab16((size_t)GG * 2*GG);
    (void)ciS2;

    __bf16* Pb      = (__bf16*)S;
    __bf16* Opart   = (__bf16*)S;
    float*  lpart   = (float*)(Opart + (size_t)NSF*NC*DM);
    __bf16* ciSbig  = simB;

    megaprep_k<<<8513, 256, 0, stream>>>(dn_W1, dn_W2, e_Win, q_W1, q_b1,
                                         Wq, Wk, Wv, bq, bk, bv,
                                         Wo, f_W1, f_W2, ci_T, ci_G, raw,
                                         dnW1T, dnW2T, eWinT, qW1pT, qb1p,
                                         Wqkv, bqkv, WoT, fW1T, fW2T,
                                         ciTT, ciGbigT, rawB, interact);

    // ---- Fused denoise1 + qualify + embed (N-concat 768, KS=4) ----
    sk(rawB, GG, dnW1T, GG, Pb, NC, 768, GG, 4, nullptr, stream);
    red(R_RELU_B16, Pb, NC, 512, 768, 0,   4, dn_b1, nullptr, 0,
        nullptr, T1b, FF, 0, nullptr, 1.f, stream);
    red(R_TANH,     Pb, NC, 128, 768, 512, 4, qb1p, nullptr, 0,
        Tq, nullptr, 128, 0, nullptr, 1.f, stream);
    red(R_BOTH,     Pb, NC, 128, 768, 640, 4, e_bin, nullptr, 0,
        h, hb, 128, 0, nullptr, 1.f, stream);
    qualify2_k<<<NC, 64, 0, stream>>>(Tq, q_W2, q_b2, quality);
    // ---- CellDenoise layer 2 ----
    sk(T1b, FF, dnW2T, FF, Pb, NC, GG, FF, 4, nullptr, stream);
    red(R_BRB16, Pb, NC, GG, GG, 0, 4, dn_b2, raw, GG, nullptr, denB, GG, 0,
        nullptr, 1.f, stream);
    // ---- Transformer layers ----
    for (int l = 0; l < LL; ++l) {
        sk(hb, DM, Wqkv + (size_t)l*384*DM, DM, Pb, NC, 384, DM, 4, nullptr, stream);
        red(R_QKVE, Pb, NC, 384, 384, 0, 4, bqkv + l*384, nullptr, 0, nullptr, qkvB, 384, 0,
            nullptr, 1.f, stream);
        tconv16_k<<<dim3(DM/32, NC/32), 256, 0, stream>>>(qkvB, 384, 256, vbT, LDV);
        flashp_k<<<dim3(NC/256, HH, NSF), 256, 0, stream>>>(qkvB, qkvB + 128, 384, vbT, LDV,
                                                            Opart, lpart);
        flashmerge_k<<<(NC*DM)/256, 256, 0, stream>>>(Opart, lpart, obB);
        sk(obB, DM, WoT + (size_t)l*DM*DM, DM, Pb, NC, DM, DM, 4, nullptr, stream);
        redln_k<<<NC, 64, 0, stream>>>(Pb, 4, bo + l*DM, h, hb,
                                       ln1_g + l*DM, ln1_b + l*DM, nullptr);
        sk(hb, DM, fW1T + (size_t)l*FF*DM, DM, Pb, NC, FF, DM, 2, nullptr, stream);
        red(R_RELU_B16, Pb, NC, FF, FF, 0, 2, f_b1 + l*FF, nullptr, 0, nullptr, T1b, FF, 0,
            nullptr, 1.f, stream);
        sk(T1b, FF, fW2T + (size_t)l*DM*FF, FF, Pb, NC, DM, FF, 8, nullptr, stream);
        // final LN of the last layer also emits sqbuf (fused rownorm)
        redln_k<<<NC, 64, 0, stream>>>(Pb, 8, f_b2 + l*DM, h, hb,
                                       ln2_g + l*DM, ln2_b + l*DM,
                                       (l == LL-1) ? sqbuf : nullptr);
    }
    // ---- CellSmooth ----
    mg(MM_DIST, hb, DM, hb, DM, quality, nullptr, simB, NC, NC, NC, DM, 1.f,
       sqbuf, nullptr, stream);
    rowsum16_k<<<NC, 256, 0, stream>>>(simB, rowinv);
    tconv16_k<<<dim3(GG/32, NC/32), 256, 0, stream>>>(denB, GG, 0, denT, NC);
    sk256(simB, NC, denT, NC, Pb, NC, GG, NC, 4, nullptr, stream);
    red(R_RS, Pb, NC, GG, GG, 0, 4, nullptr, rowinv, 0, out, smoB, GG, 0,
        nullptr, 1.f, stream);
    // ---- CellInteract ----
    tconv16_k<<<dim3(GG/32, NC/32), 256, 0, stream>>>(smoB, GG, 0, smoT, NC);
    sk(hb, DM, ciTT, DM, Pb, NC, 256, DM, 4, interact, stream);
    red(R_TEMB, Pb, NC, 256, 256, 0, 4, nullptr, nullptr, 0, nullptr, TembBig, 0, 0,
        interact, 1.f, stream);
    mg(MM_SIGSP_B16, TembBig, DM, hb, DM, nullptr,
       nullptr, ciSbig, NC, 2*NC, NC, DM, 1.f, spd, interact, stream);
    sk256(ciSbig, NC, smoT, NC, Pb, 2*NC, GG, NC, 2, interact, stream);
    red(R_CIH, Pb, 2*NC, GG, GG, 0, 2, nullptr, nullptr, 0, nullptr, Ubig, 2*GG, 0,
        interact, 1.f, stream);
    sk256(Ubig, 2*GG, ciGbigT, 2*GG, Pb, NC, GG, 2*GG, 4, interact, stream);
    red(R_ACCG, Pb, NC, GG, GG, 0, 4, nullptr, nullptr, 0, out, nullptr, GG, 0,
        interact, 1.0f/1024.f, stream);
}

// Round 17
// 494.860 us; speedup vs baseline: 1.0229x; 1.0229x over previous
//
#include <hip/hip_runtime.h>
#include <hip/hip_bf16.h>

#define NC 4096
#define GG 1024
#define DM 128
#define HH 4
#define HDIM 32
#define FF 512
#define LL 2
#define NHCI 2
#define NSF 16
#define LDV (NC+64)
#define LS2 (100.0f*100.0f)
#define QSCALE 0.17677669529663687f

typedef __bf16 bf16x8 __attribute__((ext_vector_type(8)));
typedef __bf16 bf16x4 __attribute__((ext_vector_type(4)));
typedef float  f32x4  __attribute__((ext_vector_type(4)));

// bijective XCD-chunk swizzle (m204)
__device__ __forceinline__ int xcd_swz(int orig, int nwg)
{
    int q = nwg >> 3, r = nwg & 7;
    int xcd = orig & 7, idx = orig >> 3;
    return (xcd < r ? xcd*(q+1) : r*(q+1) + (xcd-r)*q) + idx;
}

// ================= bf16 MFMA GEMM (m97 structure, fused epilogues) ==========
enum { MM_NONE=0, MM_BIAS, MM_BIAS_B16, MM_RELU_B16, MM_B16, MM_SIGSP_B16, MM_DIST };

template<int EM>
__launch_bounds__(256)
__global__ void mgemm_k(const __bf16* __restrict__ A, int lda,
                        const __bf16* __restrict__ BT, int ldb,
                        const float* __restrict__ aux1,
                        float* __restrict__ C, __bf16* __restrict__ Cb, int ldc,
                        int M, int N, int K, float alpha,
                        const float* __restrict__ aux2,
                        const int* __restrict__ flag)
{
    if (flag && *flag == 0) return;
    __shared__ __align__(16) __bf16 As[128][32];
    __shared__ __align__(16) __bf16 Bs[128][32];
    const int tid  = threadIdx.x;
    const int lane = tid & 63;
    const int wid  = tid >> 6;
    const int wm = wid >> 1, wn = wid & 1;
    const int nwg  = gridDim.x * gridDim.y;
    const int wg   = xcd_swz(blockIdx.y * gridDim.x + blockIdx.x, nwg);
    const int bm = (wg / gridDim.x) * 128, bn = (wg % gridDim.x) * 128;

    f32x4 acc[4][4];
    #pragma unroll
    for (int m=0;m<4;m++)
        #pragma unroll
        for (int n=0;n<4;n++) acc[m][n] = (f32x4){0.f,0.f,0.f,0.f};

    const int c0 = wid*64 + lane, c1 = c0 + 256;
    const __bf16* ga0 = A  + (size_t)(bm + (c0>>2))*lda + ((c0&3)<<3);
    const __bf16* ga1 = A  + (size_t)(bm + (c1>>2))*lda + ((c1&3)<<3);
    const __bf16* gb0 = BT + (size_t)(bn + (c0>>2))*ldb + ((c0&3)<<3);
    const __bf16* gb1 = BT + (size_t)(bn + (c1>>2))*ldb + ((c1&3)<<3);
    auto* lA = (__attribute__((address_space(3))) __bf16*)&As[0][0];
    auto* lB = (__attribute__((address_space(3))) __bf16*)&Bs[0][0];
    auto* lA0 = (__attribute__((address_space(3))) void*)(lA + (size_t)(wid*64)*8);
    auto* lA1 = (__attribute__((address_space(3))) void*)(lA + (size_t)(256 + wid*64)*8);
    auto* lB0 = (__attribute__((address_space(3))) void*)(lB + (size_t)(wid*64)*8);
    auto* lB1 = (__attribute__((address_space(3))) void*)(lB + (size_t)(256 + wid*64)*8);

    const int r  = lane & 15;
    const int kb = lane >> 4;
    const int arow = wm*64, brow = wn*64;

    for (int k0 = 0; k0 < K; k0 += 32) {
        __builtin_amdgcn_global_load_lds((const __attribute__((address_space(1))) void*)ga0, lA0, 16, 0, 0);
        __builtin_amdgcn_global_load_lds((const __attribute__((address_space(1))) void*)ga1, lA1, 16, 0, 0);
        __builtin_amdgcn_global_load_lds((const __attribute__((address_space(1))) void*)gb0, lB0, 16, 0, 0);
        __builtin_amdgcn_global_load_lds((const __attribute__((address_space(1))) void*)gb1, lB1, 16, 0, 0);
        ga0 += 32; ga1 += 32; gb0 += 32; gb1 += 32;
        __syncthreads();
        bf16x8 af[4], bfr[4];
        #pragma unroll
        for (int m=0;m<4;m++) af[m]  = *(const bf16x8*)&As[arow + m*16 + r][kb*8];
        #pragma unroll
        for (int n=0;n<4;n++) bfr[n] = *(const bf16x8*)&Bs[brow + n*16 + r][kb*8];
        #pragma unroll
        for (int m=0;m<4;m++)
            #pragma unroll
            for (int n=0;n<4;n++)
                acc[m][n] = __builtin_amdgcn_mfma_f32_16x16x32_bf16(af[m], bfr[n], acc[m][n], 0, 0, 0);
        __syncthreads();
    }

    const int crow = (lane >> 4) * 4;
    const int ccol = lane & 15;
    #pragma unroll
    for (int m=0;m<4;m++) {
        #pragma unroll
        for (int n=0;n<4;n++) {
            const int gn = bn + wn*64 + n*16 + ccol;
            #pragma unroll
            for (int q=0;q<4;q++) {
                const int gm = bm + wm*64 + m*16 + crow + q;
                float v = acc[m][n][q] * alpha;
                if (EM==MM_BIAS || EM==MM_BIAS_B16 || EM==MM_RELU_B16) v += aux1[gn];
                if (EM==MM_RELU_B16) v = fmaxf(v, 0.f);
                if (EM==MM_SIGSP_B16) {
                    v = 1.f/(1.f + __expf(-v));
                    v *= __expf(aux2[(size_t)(gm >> 1)*(size_t)N + gn] * (-1.f/LS2));
                }
                if (EM==MM_DIST) {
                    float d2 = fmaxf(aux2[gm] + aux2[gn] - 2.f*v, 0.f);
                    v = __expf(aux1[gn] - sqrtf(d2));
                }
                const size_t ci = (size_t)gm*ldc + gn;
                if (EM==MM_NONE || EM==MM_BIAS) C[ci] = v;
                else Cb[ci] = (__bf16)v;
            }
        }
    }
}

// ========== split-K MFMA GEMM: bf16 partials to P[ks][M][N] ================
__launch_bounds__(256)
__global__ void mgemm_sk(const __bf16* __restrict__ A, int lda,
                         const __bf16* __restrict__ BT, int ldb,
                         __bf16* __restrict__ P, int M, int N, int KC,
                         const int* __restrict__ flag)
{
    if (flag && *flag == 0) return;
    __shared__ __align__(16) __bf16 As[128][32];
    __shared__ __align__(16) __bf16 Bs[128][32];
    const int tid  = threadIdx.x;
    const int lane = tid & 63;
    const int wid  = tid >> 6;
    const int wm = wid >> 1, wn = wid & 1;
    const int nwg  = gridDim.x * gridDim.y;
    const int wg   = xcd_swz(blockIdx.y * gridDim.x + blockIdx.x, nwg);
    const int bm = (wg / gridDim.x) * 128, bn = (wg % gridDim.x) * 128;
    const size_t koff = (size_t)blockIdx.z * KC;

    f32x4 acc[4][4];
    #pragma unroll
    for (int m=0;m<4;m++)
        #pragma unroll
        for (int n=0;n<4;n++) acc[m][n] = (f32x4){0.f,0.f,0.f,0.f};

    const int c0 = wid*64 + lane, c1 = c0 + 256;
    const __bf16* ga0 = A  + (size_t)(bm + (c0>>2))*lda + koff + ((c0&3)<<3);
    const __bf16* ga1 = A  + (size_t)(bm + (c1>>2))*lda + koff + ((c1&3)<<3);
    const __bf16* gb0 = BT + (size_t)(bn + (c0>>2))*ldb + koff + ((c0&3)<<3);
    const __bf16* gb1 = BT + (size_t)(bn + (c1>>2))*ldb + koff + ((c1&3)<<3);
    auto* lA = (__attribute__((address_space(3))) __bf16*)&As[0][0];
    auto* lB = (__attribute__((address_space(3))) __bf16*)&Bs[0][0];
    auto* lA0 = (__attribute__((address_space(3))) void*)(lA + (size_t)(wid*64)*8);
    auto* lA1 = (__attribute__((address_space(3))) void*)(lA + (size_t)(256 + wid*64)*8);
    auto* lB0 = (__attribute__((address_space(3))) void*)(lB + (size_t)(wid*64)*8);
    auto* lB1 = (__attribute__((address_space(3))) void*)(lB + (size_t)(256 + wid*64)*8);

    const int r  = lane & 15;
    const int kb = lane >> 4;
    const int arow = wm*64, brow = wn*64;

    for (int k0 = 0; k0 < KC; k0 += 32) {
        __builtin_amdgcn_global_load_lds((const __attribute__((address_space(1))) void*)ga0, lA0, 16, 0, 0);
        __builtin_amdgcn_global_load_lds((const __attribute__((address_space(1))) void*)ga1, lA1, 16, 0, 0);
        __builtin_amdgcn_global_load_lds((const __attribute__((address_space(1))) void*)gb0, lB0, 16, 0, 0);
        __builtin_amdgcn_global_load_lds((const __attribute__((address_space(1))) void*)gb1, lB1, 16, 0, 0);
        ga0 += 32; ga1 += 32; gb0 += 32; gb1 += 32;
        __syncthreads();
        bf16x8 af[4], bfr[4];
        #pragma unroll
        for (int m=0;m<4;m++) af[m]  = *(const bf16x8*)&As[arow + m*16 + r][kb*8];
        #pragma unroll
        for (int n=0;n<4;n++) bfr[n] = *(const bf16x8*)&Bs[brow + n*16 + r][kb*8];
        #pragma unroll
        for (int m=0;m<4;m++)
            #pragma unroll
            for (int n=0;n<4;n++)
                acc[m][n] = __builtin_amdgcn_mfma_f32_16x16x32_bf16(af[m], bfr[n], acc[m][n], 0, 0, 0);
        __syncthreads();
    }

    __bf16* Pz = P + (size_t)blockIdx.z * M * N;
    const int crow = (lane >> 4) * 4;
    const int ccol = lane & 15;
    #pragma unroll
    for (int m=0;m<4;m++)
        #pragma unroll
        for (int n=0;n<4;n++) {
            const int gn = bn + wn*64 + n*16 + ccol;
            #pragma unroll
            for (int q=0;q<4;q++) {
                const int gm = bm + wm*64 + m*16 + crow + q;
                Pz[(size_t)gm*N + gn] = (__bf16)acc[m][n][q];
            }
        }
}

// ========== 256x256 deep-pipelined split-K GEMM (counted vmcnt) ============
__launch_bounds__(512, 1)
__global__ void mg256_sk(const __bf16* __restrict__ A, int lda,
                         const __bf16* __restrict__ BT, int ldb,
                         __bf16* __restrict__ P, int M, int N, int KC,
                         const int* __restrict__ flag)
{
    if (flag && *flag == 0) return;
    extern __shared__ __align__(16) __bf16 lds[];
    auto* L3 = (__attribute__((address_space(3))) __bf16*)lds;
    const int tid  = threadIdx.x;
    const int lane = tid & 63, w = tid >> 6;
    const int wm = w >> 2, wn = w & 3;
    const int nwg = gridDim.x * gridDim.y;
    const int wg  = xcd_swz(blockIdx.y * gridDim.x + blockIdx.x, nwg);
    const int bm = (wg / gridDim.x) * 256, bn = (wg % gridDim.x) * 256;
    const size_t koff = (size_t)blockIdx.z * KC;
    const int NT = KC / 64;
    const int r = lane & 15, kb = lane >> 4;
    const int rdk = (kb ^ ((r ^ (r >> 2)) & 3)) * 8;

    f32x4 acc[8][4];
    #pragma unroll
    for (int m=0;m<8;m++)
        #pragma unroll
        for (int n=0;n<4;n++) acc[m][n] = (f32x4){0.f,0.f,0.f,0.f};

    auto stage = [&](const __bf16* src, int ld, int brc, int kt, int s, int region) {
        #pragma unroll
        for (int j = 0; j < 2; ++j) {
            int c = j*512 + tid;
            int kc = (c & 3) ^ (((c >> 2) ^ (c >> 4)) & 3);
            const __bf16* g = src + (size_t)(brc + (c>>2))*ld + koff + (size_t)kt*64 + s*32 + (kc<<3);
            __builtin_amdgcn_global_load_lds(
                (const __attribute__((address_space(1))) void*)g,
                (__attribute__((address_space(3))) void*)(L3 + region + (j*512 + w*64)*8),
                16, 0, 0);
        }
    };
    auto ldsA = [&](int d, int s, int m) -> bf16x8 {
        return *(const bf16x8*)&lds[(d*2+s)*8192 + (wm*128 + m*16 + r)*32 + rdk];
    };
    auto ldsB = [&](int d, int s, int n) -> bf16x8 {
        return *(const bf16x8*)&lds[32768 + (d*2+s)*8192 + (wn*64 + n*16 + r)*32 + rdk];
    };

    stage(A,  lda, bm, 0, 0, 0*8192);
    stage(BT, ldb, bn, 0, 0, 32768 + 0*8192);
    stage(A,  lda, bm, 0, 1, 1*8192);
    stage(BT, ldb, bn, 0, 1, 32768 + 1*8192);
    stage(A,  lda, bm, 1, 0, 2*8192);
    stage(BT, ldb, bn, 1, 0, 32768 + 2*8192);
    asm volatile("s_waitcnt vmcnt(8)" ::: "memory");
    __builtin_amdgcn_s_barrier();

    for (int i = 0; i < NT/2; ++i) {
        const int t1 = 2*i+1, t2 = 2*i+2, t3 = 2*i+3;
        bf16x8 bf[4], af[4];

#define MG256_MFMA(MB) \
        __builtin_amdgcn_s_setprio(1); \
        _Pragma("unroll") \
        for (int mi=0; mi<4; ++mi) \
            _Pragma("unroll") \
            for (int n=0; n<4; ++n) \
                acc[MB+mi][n] = __builtin_amdgcn_mfma_f32_16x16x32_bf16(af[mi], bf[n], acc[MB+mi][n], 0, 0, 0); \
        __builtin_amdgcn_s_setprio(0);

        // ---- pair 0 ----
        #pragma unroll
        for (int n=0;n<4;n++)  bf[n] = ldsB(0,0,n);
        #pragma unroll
        for (int mi=0;mi<4;mi++) af[mi] = ldsA(0,0,mi);
        stage(A, lda, bm, t1, 1, 3*8192);
        MG256_MFMA(0)
        #pragma unroll
        for (int mi=0;mi<4;mi++) af[mi] = ldsA(0,0,4+mi);
        stage(BT, ldb, bn, t1, 1, 32768 + 3*8192);
        MG256_MFMA(4)
        asm volatile("s_waitcnt vmcnt(8)" ::: "memory");
        __builtin_amdgcn_s_barrier();

        // ---- pair 1 ----
        #pragma unroll
        for (int n=0;n<4;n++)  bf[n] = ldsB(0,1,n);
        #pragma unroll
        for (int mi=0;mi<4;mi++) af[mi] = ldsA(0,1,mi);
        if (t2 < NT) stage(A, lda, bm, t2, 0, 0*8192);
        MG256_MFMA(0)
        #pragma unroll
        for (int mi=0;mi<4;mi++) af[mi] = ldsA(0,1,4+mi);
        if (t2 < NT) stage(BT, ldb, bn, t2, 0, 32768 + 0*8192);
        MG256_MFMA(4)
        if (t2 < NT) { asm volatile("s_waitcnt vmcnt(8)" ::: "memory"); }
        else         { asm volatile("s_waitcnt vmcnt(4)" ::: "memory"); }
        __builtin_amdgcn_s_barrier();

        // ---- pair 2 ----
        #pragma unroll
        for (int n=0;n<4;n++)  bf[n] = ldsB(1,0,n);
        #pragma unroll
        for (int mi=0;mi<4;mi++) af[mi] = ldsA(1,0,mi);
        if (t2 < NT) stage(A, lda, bm, t2, 1, 1*8192);
        MG256_MFMA(0)
        #pragma unroll
        for (int mi=0;mi<4;mi++) af[mi] = ldsA(1,0,4+mi);
        if (t2 < NT) stage(BT, ldb, bn, t2, 1, 32768 + 1*8192);
        MG256_MFMA(4)
        if (t2 < NT) { asm volatile("s_waitcnt vmcnt(8)" ::: "memory"); }
        else         { asm volatile("s_waitcnt vmcnt(0)" ::: "memory"); }
        __builtin_amdgcn_s_barrier();

        // ---- pair 3 ----
        #pragma unroll
        for (int n=0;n<4;n++)  bf[n] = ldsB(1,1,n);
        #pragma unroll
        for (int mi=0;mi<4;mi++) af[mi] = ldsA(1,1,mi);
        if (t3 < NT) stage(A, lda, bm, t3, 0, 2*8192);
        MG256_MFMA(0)
        #pragma unroll
        for (int mi=0;mi<4;mi++) af[mi] = ldsA(1,1,4+mi);
        if (t3 < NT) stage(BT, ldb, bn, t3, 0, 32768 + 2*8192);
        MG256_MFMA(4)
        if (t3 < NT) { asm volatile("s_waitcnt vmcnt(8)" ::: "memory"); }
        __builtin_amdgcn_s_barrier();
#undef MG256_MFMA
    }
    asm volatile("s_waitcnt vmcnt(0)" ::: "memory");

    __bf16* Pz = P + (size_t)blockIdx.z * M * N;
    const int crow = (lane >> 4) * 4;
    const int ccol = lane & 15;
    #pragma unroll
    for (int m=0;m<8;m++)
        #pragma unroll
        for (int n=0;n<4;n++) {
            const int gn = bn + wn*64 + n*16 + ccol;
            #pragma unroll
            for (int q=0;q<4;q++) {
                const int gm = bm + wm*128 + m*16 + crow + q;
                Pz[(size_t)gm*N + gn] = (__bf16)acc[m][n][q];
            }
        }
}

// ========== split-K reduce (bf16 partials, column-sliced) ==================
enum { R_F32=0, R_B16LD, R_ACCG, R_RELU_B16, R_BRB16, R_TANH, R_BOTH, R_RS,
       R_BIAS16, R_BIASF, R_CIH, R_TEMB, R_QKVE };

template<int RE>
__launch_bounds__(256)
__global__ void redk_k(const __bf16* __restrict__ P, int M, int N, int ldp, int pcoff,
                       int KS,
                       const float* __restrict__ bias,
                       const float* __restrict__ res, int ldres,
                       float* __restrict__ C, __bf16* __restrict__ Cb,
                       int ldout, int coff,
                       const int* __restrict__ flag, float alpha)
{
    if (flag && *flag == 0) return;
    int i = blockIdx.x*256 + threadIdx.x;
    int total = (M*N) >> 2;
    if (i >= total) return;
    int row = i / (N >> 2);
    int c4  = (i - row*(N >> 2)) << 2;
    f32x4 s = {0.f,0.f,0.f,0.f};
    for (int ks = 0; ks < KS; ++ks) {
        bf16x4 t = *(const bf16x4*)(P + ((size_t)ks*M + row)*ldp + pcoff + c4);
        s[0] += (float)t[0]; s[1] += (float)t[1];
        s[2] += (float)t[2]; s[3] += (float)t[3];
    }
    #pragma unroll
    for (int j=0;j<4;j++) {
        int col = c4 + j;
        float v = s[j];
        if (RE==R_RELU_B16) v = fmaxf(v + bias[col], 0.f);
        if (RE==R_BRB16)    v = v + bias[col] + res[(size_t)row*ldres + col];
        if (RE==R_TANH)     v = tanhf(v + bias[col]);
        if (RE==R_BOTH || RE==R_BIAS16 || RE==R_BIASF) v = v + bias[col];
        if (RE==R_QKVE)   { v = v + bias[col]; if (col < 128) v *= QSCALE; }
        if (RE==R_RS)       v = v * res[row];
        size_t o = (size_t)row*ldout + coff + col;
        if (RE==R_CIH)  o = (size_t)(row >> 1)*ldout + (size_t)(row & 1)*GG + col;
        if (RE==R_TEMB) o = ((size_t)row*2 + (col >> 7))*DM + (col & 127);
        if (RE==R_F32 || RE==R_TANH || RE==R_BIASF) C[o] = v;
        if (RE==R_BOTH) { C[o] = v; Cb[o] = (__bf16)v; }
        if (RE==R_RS)   { C[o] = v; Cb[o] = (__bf16)v; }
        if (RE==R_B16LD || RE==R_RELU_B16 || RE==R_BIAS16 || RE==R_CIH || RE==R_TEMB ||
            RE==R_QKVE || RE==R_BRB16) Cb[o] = (__bf16)v;
        if (RE==R_ACCG) C[o] += v * alpha;
    }
}

// ========== fused split-K reduce + bias + residual + LayerNorm (+rownorm) ==
__launch_bounds__(64)
__global__ void redln_k(const __bf16* __restrict__ P, int KS,
                        const float* __restrict__ bias,
                        float* __restrict__ h, __bf16* __restrict__ hb,
                        const float* __restrict__ g, const float* __restrict__ b,
                        float* __restrict__ sq)
{
    int row = blockIdx.x, lane = threadIdx.x;
    float v0 = bias[lane], v1 = bias[lane + 64];
    for (int ks = 0; ks < KS; ++ks) {
        v0 += (float)P[((size_t)ks*NC + row)*DM + lane];
        v1 += (float)P[((size_t)ks*NC + row)*DM + lane + 64];
    }
    float x0 = h[row*DM + lane]      + v0;
    float x1 = h[row*DM + lane + 64] + v1;
    float s = x0 + x1, ss = x0*x0 + x1*x1;
    #pragma unroll
    for (int o=32;o>0;o>>=1) { s += __shfl_down(s, o); ss += __shfl_down(ss, o); }
    s = __shfl(s, 0); ss = __shfl(ss, 0);
    float mean = s * (1.f/128.f);
    float var  = ss * (1.f/128.f) - mean*mean;
    float inv  = rsqrtf(var + 1e-5f);
    float y0 = g[lane]      * (x0 - mean) * inv + b[lane];
    float y1 = g[lane + 64] * (x1 - mean) * inv + b[lane + 64];
    h[row*DM + lane]       = y0;  h[row*DM + lane + 64]  = y1;
    hb[row*DM + lane]      = (__bf16)y0;
    hb[row*DM + lane + 64] = (__bf16)y1;
    if (sq) {
        float t = y0*y0 + y1*y1;
        #pragma unroll
        for (int o=32;o>0;o>>=1) t += __shfl_down(t, o);
        if (lane == 0) sq[row] = t;
    }
}

// ================= flash attention, KV-split partials, no-max softmax =======
__launch_bounds__(256)
__global__ void flashp_k(const __bf16* __restrict__ Q, const __bf16* __restrict__ Kb,
                         int ldqk, const __bf16* __restrict__ VT, int ldv,
                         __bf16* __restrict__ Op, float* __restrict__ lp)
{
    __shared__ __align__(16) __bf16 Plds[4][64][68];
    const int lane = threadIdx.x & 63, w = threadIdx.x >> 6;
    const int hd = blockIdx.y, sp = blockIdx.z;
    const int q0 = blockIdx.x * 256 + w * 64;
    const int c  = lane & 15, kb = lane >> 4;

    bf16x8 aq[4];
    #pragma unroll
    for (int qs=0;qs<4;qs++)
        aq[qs] = *(const bf16x8*)&Q[(size_t)(q0 + qs*16 + c)*ldqk + hd*HDIM + kb*8];
    bf16x8 ones;
    #pragma unroll
    for (int j=0;j<8;j++) ones[j] = (__bf16)1.0f;

    f32x4 oacc[4][2];
    f32x4 lacc[4];
    #pragma unroll
    for (int qs=0;qs<4;qs++) {
        oacc[qs][0] = (f32x4){0,0,0,0}; oacc[qs][1] = (f32x4){0,0,0,0};
        lacc[qs] = (f32x4){0,0,0,0};
    }

    const int kv0 = sp * (NC/NSF), kv1 = kv0 + NC/NSF;
    for (int kv = kv0; kv < kv1; kv += 64) {
        bf16x8 bk[4];
        #pragma unroll
        for (int n=0;n<4;n++)
            bk[n] = *(const bf16x8*)&Kb[(size_t)(kv + n*16 + c)*ldqk + hd*HDIM + kb*8];
        bf16x8 bv[2][2];
        #pragma unroll
        for (int ks=0;ks<2;ks++)
            #pragma unroll
            for (int n2=0;n2<2;n2++)
                bv[ks][n2] = *(const bf16x8*)&VT[(size_t)(hd*HDIM + n2*16 + c)*ldv + kv + ks*32 + kb*8];
        #pragma unroll
        for (int qs=0;qs<4;qs++) {
            f32x4 s[4];
            #pragma unroll
            for (int n=0;n<4;n++)
                s[n] = __builtin_amdgcn_mfma_f32_16x16x32_bf16(aq[qs], bk[n], (f32x4){0,0,0,0}, 0, 0, 0);
            #pragma unroll
            for (int n=0;n<4;n++)
                #pragma unroll
                for (int q=0;q<4;q++)
                    Plds[w][qs*16 + kb*4 + q][n*16 + c] = (__bf16)__expf(s[n][q]);
        }
        #pragma unroll
        for (int qs=0;qs<4;qs++)
            #pragma unroll
            for (int ks=0;ks<2;ks++) {
                bf16x8 ap = *(const bf16x8*)&Plds[w][qs*16 + c][ks*32 + kb*8];
                #pragma unroll
                for (int n2=0;n2<2;n2++)
                    oacc[qs][n2] = __builtin_amdgcn_mfma_f32_16x16x32_bf16(ap, bv[ks][n2], oacc[qs][n2], 0, 0, 0);
                lacc[qs] = __builtin_amdgcn_mfma_f32_16x16x32_bf16(ap, ones, lacc[qs], 0, 0, 0);
            }
    }
    __bf16* Oz = Op + (size_t)sp * NC * DM;
    #pragma unroll
    for (int qs=0;qs<4;qs++)
        #pragma unroll
        for (int n2=0;n2<2;n2++)
            #pragma unroll
            for (int q=0;q<4;q++)
                Oz[(size_t)(q0 + qs*16 + kb*4 + q)*DM + hd*HDIM + n2*16 + c] = (__bf16)oacc[qs][n2][q];
    if (c == 0) {
        #pragma unroll
        for (int qs=0;qs<4;qs++)
            #pragma unroll
            for (int q=0;q<4;q++)
                lp[((size_t)sp*HH + hd)*NC + q0 + qs*16 + kb*4 + q] = lacc[qs][q];
    }
}

// merge NSF partials -> O bf16 [NC][DM]
__launch_bounds__(256)
__global__ void flashmerge_k(const __bf16* __restrict__ Op, const float* __restrict__ lp,
                             __bf16* __restrict__ O)
{
    int idx = blockIdx.x*256 + threadIdx.x;
    int row = idx >> 7, col = idx & 127, hd = col >> 5;
    float L = 0.f, acc = 0.f;
    #pragma unroll
    for (int s=0;s<NSF;s++) {
        L   += lp[((size_t)s*HH + hd)*NC + row];
        acc += (float)Op[(size_t)s*NC*DM + idx];
    }
    O[idx] = (__bf16)(acc / L);
}

// ================= megaprep: all weight packs in ONE launch =================
__device__ __forceinline__ void tconv32(float (*tile)[33],
                                        const float* __restrict__ in,
                                        __bf16* __restrict__ out,
                                        int R, int C, int ldout, int coff, int t)
{
    int tx = threadIdx.x & 31, ty = threadIdx.x >> 5;
    int bx = t % (C/32), by = t / (C/32);
    int bc = bx*32, br = by*32;
    #pragma unroll
    for (int i=0;i<4;i++)
        tile[ty + 8*i][tx] = in[(size_t)(br + ty + 8*i)*C + bc + tx];
    __syncthreads();
    #pragma unroll
    for (int i=0;i<4;i++)
        out[(size_t)(bc + ty + 8*i)*ldout + coff + br + tx] = (__bf16)tile[tx][ty + 8*i];
}

__launch_bounds__(256)
__global__ void megaprep_k(const float* __restrict__ dn_W1, const float* __restrict__ dn_W2,
                           const float* __restrict__ e_Win, const float* __restrict__ q_W1,
                           const float* __restrict__ q_b1,
                           const float* __restrict__ Wq, const float* __restrict__ Wk,
                           const float* __restrict__ Wv,
                           const float* __restrict__ bq, const float* __restrict__ bk,
                           const float* __restrict__ bv,
                           const float* __restrict__ Wo, const float* __restrict__ f_W1,
                           const float* __restrict__ f_W2,
                           const float* __restrict__ ci_T, const float* __restrict__ ci_G,
                           const float* __restrict__ raw,
                           __bf16* __restrict__ dnW1T, __bf16* __restrict__ dnW2T,
                           __bf16* __restrict__ eWinT, __bf16* __restrict__ qW1pT,
                           float* __restrict__ qb1p,
                           __bf16* __restrict__ Wqkv, float* __restrict__ bqkv,
                           __bf16* __restrict__ WoT, __bf16* __restrict__ fW1T,
                           __bf16* __restrict__ fW2T, __bf16* __restrict__ ciTT,
                           __bf16* __restrict__ ciGbigT, __bf16* __restrict__ rawB,
                           const int* __restrict__ interact)
{
    __shared__ float tile[32][33];
    int t = blockIdx.x;
    if (t < 512) { tconv32(tile, dn_W1, dnW1T, GG, FF, GG, 0, t); return; }
    t -= 512;
    if (t < 512) { tconv32(tile, dn_W2, dnW2T, FF, GG, FF, 0, t); return; }
    t -= 512;
    if (t < 128) { tconv32(tile, e_Win, eWinT, GG, DM, GG, 0, t); return; }
    t -= 128;
    if (t < 512) {
        int idx = t*256 + threadIdx.x;
        int k = idx & 1023, j = idx >> 10;
        qW1pT[(size_t)j*GG + k] = (j < 64) ? (__bf16)q_W1[(size_t)k*64 + j] : (__bf16)0.f;
        return;
    }
    t -= 512;
    if (t < 1) {
        if (threadIdx.x < 128) qb1p[threadIdx.x] = (threadIdx.x < 64) ? q_b1[threadIdx.x] : 0.f;
        return;
    }
    t -= 1;
    if (t < 384) {
        int l = t / 192;
        int i = (t % 192)*256 + threadIdx.x;
        int n = i >> 7, k = i & 127;
        const float* W = (n < 128) ? Wq : (n < 256 ? Wk : Wv);
        Wqkv[(size_t)l*384*128 + i] = (__bf16)W[(size_t)l*DM*DM + (size_t)k*DM + (n & 127)];
        if (i < 384) {
            const float* b = (i < 128) ? bq : (i < 256 ? bk : bv);
            bqkv[l*384 + i] = b[l*DM + (i & 127)];
        }
        return;
    }
    t -= 384;
    if (t < 32) { int l = t/16; tconv32(tile, Wo + (size_t)l*DM*DM, WoT + (size_t)l*DM*DM, DM, DM, DM, 0, t%16); return; }
    t -= 32;
    if (t < 128) { int l = t/64; tconv32(tile, f_W1 + (size_t)l*DM*FF, fW1T + (size_t)l*FF*DM, DM, FF, DM, 0, t%64); return; }
    t -= 128;
    if (t < 128) { int l = t/64; tconv32(tile, f_W2 + (size_t)l*FF*DM, fW2T + (size_t)l*DM*FF, FF, DM, FF, 0, t%64); return; }
    t -= 128;
    if (t < 32) {
        if (*interact) { int l = t/16; tconv32(tile, ci_T + (size_t)l*DM*DM, ciTT + (size_t)l*DM*DM, DM, DM, DM, 0, t%16); }
        return;
    }
    t -= 32;
    if (t < 2048) {
        if (*interact) { int hh = t/1024; tconv32(tile, ci_G + (size_t)hh*GG*GG, ciGbigT, GG, GG, 2*GG, hh*GG, t%1024); }
        return;
    }
    t -= 2048;
    {
        int i = t*256 + threadIdx.x;
        float4 v = ((const float4*)raw)[i];
        bf16x4 o = {(__bf16)v.x, (__bf16)v.y, (__bf16)v.z, (__bf16)v.w};
        ((bf16x4*)rawB)[i] = o;
    }
}

// ================= small kernels =================
__global__ void qualify2_k(const float* __restrict__ Tq, const float* __restrict__ w,
                           const float* __restrict__ b2, float* __restrict__ quality)
{
    int row = blockIdx.x, lane = threadIdx.x;
    float v = Tq[row*128 + lane] * w[lane];
    #pragma unroll
    for (int o=32;o>0;o>>=1) v += __shfl_down(v, o);
    if (lane == 0) quality[row] = v + b2[0];
}

__launch_bounds__(256)
__global__ void rowsum16_k(const __bf16* __restrict__ P, float* __restrict__ rinv)
{
    __shared__ float sl[4];
    size_t row = blockIdx.x;
    const __bf16* p = P + row * (size_t)NC;
    int tid = threadIdx.x;
    float sum = 0.f;
    for (int j = tid*8; j < NC; j += 256*8) {
        bf16x8 v = *(const bf16x8*)&p[j];
        #pragma unroll
        for (int k=0;k<8;k++) sum += (float)v[k];
    }
    #pragma unroll
    for (int o=32;o>0;o>>=1) sum += __shfl_down(sum, o);
    if ((tid & 63) == 0) sl[tid >> 6] = sum;
    __syncthreads();
    if (tid == 0) rinv[row] = 1.f / (sl[0] + sl[1] + sl[2] + sl[3]);
}

__global__ void tconv16_k(const __bf16* __restrict__ in, int ldin, int coff,
                          __bf16* __restrict__ out, int ldout)
{
    __shared__ __bf16 tile[32][33];
    int bc = blockIdx.x * 32, br = blockIdx.y * 32;
    int tx = threadIdx.x & 31, ty = threadIdx.x >> 5;
    #pragma unroll
    for (int i=0;i<4;i++)
        tile[ty + 8*i][tx] = in[(size_t)(br + ty + 8*i)*ldin + coff + bc + tx];
    __syncthreads();
    #pragma unroll
    for (int i=0;i<4;i++)
        out[(size_t)(bc + ty + 8*i)*ldout + br + tx] = tile[tx][ty + 8*i];
}

// ================= launchers =================
static void mg(int em, const __bf16* A, int lda, const __bf16* BT, int ldb,
               const float* aux1, float* C, __bf16* Cb, int ldc,
               int M, int N, int K, float alpha,
               const float* aux2, const int* flag, hipStream_t s)
{
    dim3 grid(N/128, M/128), block(256);
#define MGL(E) mgemm_k<E><<<grid,block,0,s>>>(A,lda,BT,ldb,aux1,C,Cb,ldc,M,N,K,alpha,aux2,flag)
    switch (em) {
        case MM_NONE:      MGL(MM_NONE);      break;
        case MM_BIAS:      MGL(MM_BIAS);      break;
        case MM_BIAS_B16:  MGL(MM_BIAS_B16);  break;
        case MM_RELU_B16:  MGL(MM_RELU_B16);  break;
        case MM_B16:       MGL(MM_B16);       break;
        case MM_SIGSP_B16: MGL(MM_SIGSP_B16); break;
        case MM_DIST:      MGL(MM_DIST);      break;
    }
#undef MGL
}

static void sk(const __bf16* A, int lda, const __bf16* BT, int ldb,
               __bf16* P, int M, int N, int K, int KS, const int* flag, hipStream_t s)
{
    dim3 grid(N/128, M/128, KS), block(256);
    mgemm_sk<<<grid, block, 0, s>>>(A, lda, BT, ldb, P, M, N, K/KS, flag);
}

static void sk256(const __bf16* A, int lda, const __bf16* BT, int ldb,
                  __bf16* P, int M, int N, int K, int KS, const int* flag, hipStream_t s)
{
    dim3 grid(N/256, M/256, KS), block(512);
    mg256_sk<<<grid, block, 131072, s>>>(A, lda, BT, ldb, P, M, N, K/KS, flag);
}

static void red(int re, const __bf16* P, int M, int N, int ldp, int pcoff, int KS,
                const float* bias, const float* res, int ldres,
                float* C, __bf16* Cb, int ldout, int coff,
                const int* flag, float alpha, hipStream_t s)
{
    int blocks = (M*N/4 + 255) / 256;
#define RDL(E) redk_k<E><<<blocks,256,0,s>>>(P,M,N,ldp,pcoff,KS,bias,res,ldres,C,Cb,ldout,coff,flag,alpha)
    switch (re) {
        case R_F32:      RDL(R_F32);      break;
        case R_B16LD:    RDL(R_B16LD);    break;
        case R_ACCG:     RDL(R_ACCG);     break;
        case R_RELU_B16: RDL(R_RELU_B16); break;
        case R_BRB16:    RDL(R_BRB16);    break;
        case R_TANH:     RDL(R_TANH);     break;
        case R_BOTH:     RDL(R_BOTH);     break;
        case R_RS:       RDL(R_RS);       break;
        case R_BIAS16:   RDL(R_BIAS16);   break;
        case R_BIASF:    RDL(R_BIASF);    break;
        case R_CIH:      RDL(R_CIH);      break;
        case R_TEMB:     RDL(R_TEMB);     break;
        case R_QKVE:     RDL(R_QKVE);     break;
    }
#undef RDL
}

extern "C" void kernel_launch(void* const* d_in, const int* in_sizes, int n_in,
                              void* d_out, int out_size, void* d_ws, size_t ws_size,
                              hipStream_t stream)
{
    const float* raw   = (const float*)d_in[0];
    const float* spd   = (const float*)d_in[1];
    const float* dn_W1 = (const float*)d_in[2];
    const float* dn_b1 = (const float*)d_in[3];
    const float* dn_W2 = (const float*)d_in[4];
    const float* dn_b2 = (const float*)d_in[5];
    const float* q_W1  = (const float*)d_in[6];
    const float* q_b1  = (const float*)d_in[7];
    const float* q_W2  = (const float*)d_in[8];
    const float* q_b2  = (const float*)d_in[9];
    const float* e_Win = (const float*)d_in[10];
    const float* e_bin = (const float*)d_in[11];
    const float* Wq    = (const float*)d_in[12];
    const float* Wk    = (const float*)d_in[13];
    const float* Wv    = (const float*)d_in[14];
    const float* Wo    = (const float*)d_in[15];
    const float* bq    = (const float*)d_in[16];
    const float* bk    = (const float*)d_in[17];
    const float* bv    = (const float*)d_in[18];
    const float* bo    = (const float*)d_in[19];
    const float* ln1_g = (const float*)d_in[20];
    const float* ln1_b = (const float*)d_in[21];
    const float* ln2_g = (const float*)d_in[22];
    const float* ln2_b = (const float*)d_in[23];
    const float* f_W1  = (const float*)d_in[24];
    const float* f_b1  = (const float*)d_in[25];
    const float* f_W2  = (const float*)d_in[26];
    const float* f_b2  = (const float*)d_in[27];
    const float* ci_T  = (const float*)d_in[28];
    const float* ci_G  = (const float*)d_in[29];
    const int*   interact = (const int*)d_in[30];
    (void)in_sizes; (void)n_in; (void)ws_size; (void)out_size;

    (void)hipFuncSetAttribute((const void*)mg256_sk,
                              hipFuncAttributeMaxDynamicSharedMemorySize, 131072);

    float* out = (float*)d_out;
    float* ws = (float*)d_ws;
    size_t off = 0;
    auto af32 = [&](size_t n) { float* p = ws + off; off += n; return p; };
    auto ab16 = [&](size_t n) { __bf16* p = (__bf16*)(ws + off); off += (n + 1) / 2; return p; };

    float*  S        = af32((size_t)NC * NC);
    __bf16* simB     = ab16((size_t)NC * NC);
    __bf16* ciS2     = ab16((size_t)NC * NC);
    __bf16* denB     = ab16((size_t)NC * GG);
    __bf16* smoB     = ab16((size_t)NC * GG);
    __bf16* T1b      = ab16((size_t)NC * FF);
    float*  Tq       = af32((size_t)NC * 128);
    float*  quality  = af32(NC);
    float*  rowinv   = af32(NC);
    float*  h        = af32((size_t)NC * DM);
    __bf16* hb       = ab16((size_t)NC * DM);
    __bf16* qkvB     = ab16((size_t)NC * 384);
    __bf16* vbT      = ab16((size_t)DM * LDV);
    __bf16* obB      = ab16((size_t)NC * DM);
    __bf16* rawB     = ab16((size_t)NC * GG);
    __bf16* denT     = ab16((size_t)GG * NC);
    __bf16* smoT     = ab16((size_t)GG * NC);
    __bf16* Ubig     = ab16((size_t)NC * 2*GG);
    __bf16* TembBig  = ab16((size_t)NHCI * NC * DM);
    float*  sqbuf    = af32(NC);
    __bf16* dnW1T    = ab16((size_t)768 * GG);          // Wcat = [dnW1T;qW1pT;eWinT]
    __bf16* qW1pT    = dnW1T + (size_t)512 * GG;
    __bf16* eWinT    = dnW1T + (size_t)640 * GG;
    __bf16* dnW2T    = ab16((size_t)GG * FF);
    float*  qb1p     = af32(128);
    __bf16* Wqkv     = ab16((size_t)LL * 384 * DM);
    float*  bqkv     = af32((size_t)LL * 384);
    __bf16* WoT      = ab16((size_t)LL * DM * DM);
    __bf16* fW1T     = ab16((size_t)LL * FF * DM);
    __bf16* fW2T     = ab16((size_t)LL * DM * FF);
    __bf16* ciTT     = ab16((size_t)NHCI * DM * DM);
    __bf16* ciGbigT  = ab16((size_t)GG * 2*GG);
    (void)ciS2;

    __bf16* Pb      = (__bf16*)S;
    __bf16* Opart   = (__bf16*)S;
    float*  lpart   = (float*)(Opart + (size_t)NSF*NC*DM);
    __bf16* ciSbig  = simB;

    megaprep_k<<<8513, 256, 0, stream>>>(dn_W1, dn_W2, e_Win, q_W1, q_b1,
                                         Wq, Wk, Wv, bq, bk, bv,
                                         Wo, f_W1, f_W2, ci_T, ci_G, raw,
                                         dnW1T, dnW2T, eWinT, qW1pT, qb1p,
                                         Wqkv, bqkv, WoT, fW1T, fW2T,
                                         ciTT, ciGbigT, rawB, interact);

    // ---- Fused denoise1 + qualify + embed (N-concat 768, KS=4) ----
    sk(rawB, GG, dnW1T, GG, Pb, NC, 768, GG, 4, nullptr, stream);
    red(R_RELU_B16, Pb, NC, 512, 768, 0,   4, dn_b1, nullptr, 0,
        nullptr, T1b, FF, 0, nullptr, 1.f, stream);
    red(R_TANH,     Pb, NC, 128, 768, 512, 4, qb1p, nullptr, 0,
        Tq, nullptr, 128, 0, nullptr, 1.f, stream);
    red(R_BOTH,     Pb, NC, 128, 768, 640, 4, e_bin, nullptr, 0,
        h, hb, 128, 0, nullptr, 1.f, stream);
    qualify2_k<<<NC, 64, 0, stream>>>(Tq, q_W2, q_b2, quality);
    // ---- CellDenoise layer 2 ----
    sk(T1b, FF, dnW2T, FF, Pb, NC, GG, FF, 4, nullptr, stream);
    red(R_BRB16, Pb, NC, GG, GG, 0, 4, dn_b2, raw, GG, nullptr, denB, GG, 0,
        nullptr, 1.f, stream);
    // ---- Transformer layers ----
    for (int l = 0; l < LL; ++l) {
        sk(hb, DM, Wqkv + (size_t)l*384*DM, DM, Pb, NC, 384, DM, 2, nullptr, stream);
        red(R_QKVE, Pb, NC, 384, 384, 0, 2, bqkv + l*384, nullptr, 0, nullptr, qkvB, 384, 0,
            nullptr, 1.f, stream);
        tconv16_k<<<dim3(DM/32, NC/32), 256, 0, stream>>>(qkvB, 384, 256, vbT, LDV);
        flashp_k<<<dim3(NC/256, HH, NSF), 256, 0, stream>>>(qkvB, qkvB + 128, 384, vbT, LDV,
                                                            Opart, lpart);
        flashmerge_k<<<(NC*DM)/256, 256, 0, stream>>>(Opart, lpart, obB);
        sk(obB, DM, WoT + (size_t)l*DM*DM, DM, Pb, NC, DM, DM, 4, nullptr, stream);
        redln_k<<<NC, 64, 0, stream>>>(Pb, 4, bo + l*DM, h, hb,
                                       ln1_g + l*DM, ln1_b + l*DM, nullptr);
        sk(hb, DM, fW1T + (size_t)l*FF*DM, DM, Pb, NC, FF, DM, 2, nullptr, stream);
        red(R_RELU_B16, Pb, NC, FF, FF, 0, 2, f_b1 + l*FF, nullptr, 0, nullptr, T1b, FF, 0,
            nullptr, 1.f, stream);
        sk(T1b, FF, fW2T + (size_t)l*DM*FF, FF, Pb, NC, DM, FF, 4, nullptr, stream);
        redln_k<<<NC, 64, 0, stream>>>(Pb, 4, f_b2 + l*DM, h, hb,
                                       ln2_g + l*DM, ln2_b + l*DM,
                                       (l == LL-1) ? sqbuf : nullptr);
    }
    // ---- CellSmooth ----
    mg(MM_DIST, hb, DM, hb, DM, quality, nullptr, simB, NC, NC, NC, DM, 1.f,
       sqbuf, nullptr, stream);
    rowsum16_k<<<NC, 256, 0, stream>>>(simB, rowinv);
    tconv16_k<<<dim3(GG/32, NC/32), 256, 0, stream>>>(denB, GG, 0, denT, NC);
    sk256(simB, NC, denT, NC, Pb, NC, GG, NC, 4, nullptr, stream);
    red(R_RS, Pb, NC, GG, GG, 0, 4, nullptr, rowinv, 0, out, smoB, GG, 0,
        nullptr, 1.f, stream);
    // ---- CellInteract ----
    tconv16_k<<<dim3(GG/32, NC/32), 256, 0, stream>>>(smoB, GG, 0, smoT, NC);
    sk(hb, DM, ciTT, DM, Pb, NC, 256, DM, 4, interact, stream);
    red(R_TEMB, Pb, NC, 256, 256, 0, 4, nullptr, nullptr, 0, nullptr, TembBig, 0, 0,
        interact, 1.f, stream);
    mg(MM_SIGSP_B16, TembBig, DM, hb, DM, nullptr,
       nullptr, ciSbig, NC, 2*NC, NC, DM, 1.f, spd, interact, stream);
    sk256(ciSbig, NC, smoT, NC, Pb, 2*NC, GG, NC, 2, interact, stream);
    red(R_CIH, Pb, 2*NC, GG, GG, 0, 2, nullptr, nullptr, 0, nullptr, Ubig, 2*GG, 0,
        interact, 1.f, stream);
    sk256(Ubig, 2*GG, ciGbigT, 2*GG, Pb, NC, GG, 2*GG, 4, interact, stream);
    red(R_ACCG, Pb, NC, GG, GG, 0, 4, nullptr, nullptr, 0, out, nullptr, GG, 0,
        interact, 1.0f/1024.f, stream);
}